// Round 1
// baseline (4953.176 us; speedup 1.0000x reference)
//
#include <hip/hip_runtime.h>
#include <cstdint>
#include <cstddef>

#define B 64
#define H 1024
#define V 32000
#define T 50
#define VT 2000          // V/16 tiles
#define GNT 256          // 4096/16 gate col tiles
#define SW 16.0f         // weight pre-scale (avoid fp16 subnormals)
#define SL 2048.0f       // lo-word scale
#define INV_HI (1.0f/16.0f)
#define INV_LO (1.0f/32768.0f)

typedef _Float16 f16;
typedef _Float16 half8 __attribute__((ext_vector_type(8)));
typedef float f32x4 __attribute__((ext_vector_type(4)));

__device__ __forceinline__ float sigmoidf_(float x) { return 1.0f / (1.0f + expf(-x)); }

// Fragment index helpers (16x16x32 f16 MFMA):
// A: lane holds A[m=lane&15][k=quad*8+j]   -> A_pack[((chunk*4+mt)*64+lane)*8+j]
// B: lane holds B[k=quad*8+j][n=lane&15]   -> W_pack[((ntile*NCH+chunk)*64+lane)*8+j]
// C/D: col(n)=lane&15, row(m)=quad*4+reg   [measured m89/m91]

// ---------------------------------------------------------------------------
// pack out_w [H][V] fp32 -> hi/lo fp16 B-fragments (scaled by SW, lo by SL)
// ---------------------------------------------------------------------------
__global__ __launch_bounds__(256) void k_packw(const float* __restrict__ out_w,
                                               f16* __restrict__ Whi, f16* __restrict__ Wlo)
{
    const int vt = blockIdx.x >> 3, cg = blockIdx.x & 7;
    const int chunk = cg * 4 + (threadIdx.x >> 6);
    const int q = (threadIdx.x >> 4) & 3, vl = threadIdx.x & 15;
    const int lane = q * 16 + vl;
    half8 h8, l8;
    #pragma unroll
    for (int j = 0; j < 8; ++j) {
        const int k = chunk * 32 + q * 8 + j;
        // one-shot fp32 read: keep it out of L3 (weights' packed form is the hot set)
        const float w = __builtin_nontemporal_load(&out_w[(size_t)k * V + vt * 16 + vl]) * SW;
        const f16 hi = (f16)w;
        h8[j] = hi;
        l8[j] = (f16)((w - (float)hi) * SL);
    }
    const size_t pos = ((size_t)(vt * 32 + chunk) * 64 + lane) * 8;
    *(half8*)&Whi[pos] = h8;
    *(half8*)&Wlo[pos] = l8;
}

// ---------------------------------------------------------------------------
// pack gate weights: W_cat[K=2048][N'=4096], K<1024 -> w_ih, else w_hh.
// column permutation: n' = blk*16 + kk*4 + g  <->  (g, k = blk*4+kk)
// ---------------------------------------------------------------------------
__global__ __launch_bounds__(256) void k_packg(const float* __restrict__ w_ih,
                                               const float* __restrict__ w_hh,
                                               f16* __restrict__ Ghi, f16* __restrict__ Glo)
{
    const int nt = blockIdx.x >> 4, cg = blockIdx.x & 15;
    const int chunk = cg * 4 + (threadIdx.x >> 6);
    const int q = (threadIdx.x >> 4) & 3, vl = threadIdx.x & 15;
    const int lane = q * 16 + vl;
    const int kk = vl >> 2, g = vl & 3;
    const int kcol = nt * 4 + kk;
    half8 h8, l8;
    #pragma unroll
    for (int j = 0; j < 8; ++j) {
        const int K = chunk * 32 + q * 8 + j;
        const float w = ((K < 1024)
            ? __builtin_nontemporal_load(&w_ih[(size_t)g * H * H + (size_t)K * H + kcol])
            : __builtin_nontemporal_load(&w_hh[(size_t)g * H * H + (size_t)(K - 1024) * H + kcol])) * SW;
        const f16 hi = (f16)w;
        h8[j] = hi;
        l8[j] = (f16)((w - (float)hi) * SL);
    }
    const size_t pos = ((size_t)(nt * 64 + chunk) * 64 + lane) * 8;
    *(half8*)&Ghi[pos] = h8;
    *(half8*)&Glo[pos] = l8;
}

// ---------------------------------------------------------------------------
// init: transpose h,c; pack h -> Ah[0]; pack emb[SOS=1] -> Ax; flags; biasp.
// blocks 0..63 = per-b, block 64 = misc, blocks 65..80 = bias pack.
// ---------------------------------------------------------------------------
__global__ void k_init(const float* __restrict__ h_in, const float* __restrict__ c_in,
                       const float* __restrict__ emb,
                       const float* __restrict__ b_ih, const float* __restrict__ b_hh,
                       float* __restrict__ h_t, float* __restrict__ c_t,
                       f16* __restrict__ Axh, f16* __restrict__ Axl,
                       f16* __restrict__ Ah0h, f16* __restrict__ Ah0l,
                       unsigned long long* __restrict__ keys, int* __restrict__ active,
                       int* __restrict__ cnt, float* __restrict__ out,
                       float* __restrict__ biasp)
{
    if (blockIdx.x >= 65) {
        const int n = (blockIdx.x - 65) * 256 + threadIdx.x;   // 4096
        const int blk = n >> 4, rem = n & 15, kk = rem >> 2, g = rem & 3;
        const int kcol = blk * 4 + kk;
        biasp[n] = b_ih[g * H + kcol] + b_hh[g * H + kcol];
        return;
    }
    if (blockIdx.x == 64) {
        for (int i = threadIdx.x; i < T * B; i += 256) out[i] = 0.0f;
        if (threadIdx.x < B) keys[threadIdx.x] = 0ull;
        if (threadIdx.x == 0) { active[0] = 1; active[1] = 0; cnt[0] = 0; }
        return;
    }
    const int b = blockIdx.x, mt = b >> 4;
    #pragma unroll
    for (int i = 0; i < 4; ++i) {
        const int k = threadIdx.x * 4 + i;
        const float hv = h_in[b * H + k];
        const float cv = c_in[b * H + k];
        h_t[k * B + b] = hv;
        c_t[k * B + b] = cv;
        const float xv = emb[H + k];            // SOS token row = 1
        const int chunk = k >> 5, lane = ((k >> 3) & 3) * 16 + (b & 15), j = k & 7;
        const size_t pos = ((size_t)(chunk * 4 + mt) * 64 + lane) * 8 + j;
        f16 hi = (f16)hv;
        Ah0h[pos] = hi; Ah0l[pos] = (f16)((hv - (float)hi) * SL);
        hi = (f16)xv;
        Axh[pos] = hi; Axl[pos] = (f16)((xv - (float)hi) * SL);
    }
}

// ---------------------------------------------------------------------------
// gates: C[64 b][16 n'] per block (n' = 4 k-cols x 4 gates), K=2048 split
// across 4 waves; fused bias + activations + c/h update + h-pack epilogue.
// ---------------------------------------------------------------------------
__global__ __launch_bounds__(256) void k_gates(
    const f16* __restrict__ Ghi, const f16* __restrict__ Glo,
    const f16* __restrict__ Axh, const f16* __restrict__ Axl,
    const f16* __restrict__ Ahh, const f16* __restrict__ Ahl,   // read (cur)
    f16* __restrict__ Anh, f16* __restrict__ Anl,               // write (next)
    const float* __restrict__ biasp, float* __restrict__ h_t, float* __restrict__ c_t,
    const int* __restrict__ active, int t)
{
    if (!active[t & 1]) return;
    const int tid = threadIdx.x;
    const int s = tid >> 6, lane = tid & 63;
    const int quad = lane >> 4, vl = lane & 15;
    const int nt = blockIdx.x;

    f32x4 acc0[4], acc1[4];
    #pragma unroll
    for (int mt = 0; mt < 4; ++mt) {
        acc0[mt] = (f32x4){0.f, 0.f, 0.f, 0.f};
        acc1[mt] = (f32x4){0.f, 0.f, 0.f, 0.f};
    }

    for (int c = s * 16; c < s * 16 + 16; ++c) {
        const f16* ah = (c < 32) ? Axh : Ahh;
        const f16* al = (c < 32) ? Axl : Ahl;
        const int cc = c & 31;
        const size_t wpos = ((size_t)(nt * 64 + c) * 64 + lane) * 8;
        const half8 whi = *(const half8*)&Ghi[wpos];
        const half8 wlo = *(const half8*)&Glo[wpos];
        #pragma unroll
        for (int mt = 0; mt < 4; ++mt) {
            const size_t apos = ((size_t)(cc * 4 + mt) * 64 + lane) * 8;
            const half8 ahi = *(const half8*)&ah[apos];
            const half8 alo = *(const half8*)&al[apos];
            acc0[mt] = __builtin_amdgcn_mfma_f32_16x16x32_f16(ahi, whi, acc0[mt], 0, 0, 0);
            acc1[mt] = __builtin_amdgcn_mfma_f32_16x16x32_f16(ahi, wlo, acc1[mt], 0, 0, 0);
            acc1[mt] = __builtin_amdgcn_mfma_f32_16x16x32_f16(alo, whi, acc1[mt], 0, 0, 0);
        }
    }

    __shared__ float red[4][64][16];   // [k-split][b][n'loc]
    __shared__ float gsum[64][17];
    #pragma unroll
    for (int mt = 0; mt < 4; ++mt)
        #pragma unroll
        for (int r = 0; r < 4; ++r)
            red[s][mt * 16 + quad * 4 + r][vl] = acc0[mt][r] * INV_HI + acc1[mt][r] * INV_LO;
    __syncthreads();
    #pragma unroll
    for (int i = 0; i < 4; ++i) {
        const int p = i * 256 + tid;
        const int b = p >> 4, v2 = p & 15;
        gsum[b][v2] = red[0][b][v2] + red[1][b][v2] + red[2][b][v2] + red[3][b][v2]
                    + biasp[nt * 16 + v2];
    }
    __syncthreads();
    {
        const int kk = tid >> 6, b = tid & 63;
        const float ig = sigmoidf_(gsum[b][kk * 4 + 0]);
        const float fg = sigmoidf_(gsum[b][kk * 4 + 1]);
        const float cg = tanhf(gsum[b][kk * 4 + 2]);
        const float og = sigmoidf_(gsum[b][kk * 4 + 3]);
        const int k = nt * 4 + kk;
        const float cv = c_t[k * B + b];
        const float cn = fg * cv + ig * cg;
        const float hn = og * tanhf(cn);
        c_t[k * B + b] = cn;
        h_t[k * B + b] = hn;
        const int chunk = k >> 5, mt = b >> 4, lane2 = ((k >> 3) & 3) * 16 + (b & 15), j = k & 7;
        const size_t pos = ((size_t)(chunk * 4 + mt) * 64 + lane2) * 8 + j;
        const f16 hi = (f16)hn;
        Anh[pos] = hi;
        Anl[pos] = (f16)((hn - (float)hi) * SL);
    }
}

// ---------------------------------------------------------------------------
// logits: block = 64 v-cols (wave w -> 16), M=64, K=1024; fused +out_b +std
// + packed-key argmax (atomicMax into keys[b]) + LAST-BLOCK finalize:
// decode argmax -> token, out write, active update, emb gather + Ax pack.
// ---------------------------------------------------------------------------
__global__ __launch_bounds__(256) void k_logits(
    const f16* __restrict__ Ahh, const f16* __restrict__ Ahl,
    const f16* __restrict__ Whi, const f16* __restrict__ Wlo,
    const float* __restrict__ out_b, const float* __restrict__ std_,
    const float* __restrict__ emb,
    unsigned long long* __restrict__ keys, int* __restrict__ active,
    int* __restrict__ cnt, float* __restrict__ out,
    f16* __restrict__ Axh, f16* __restrict__ Axl, int t)
{
    const int cur = t & 1;
    if (blockIdx.x == 0 && threadIdx.x == 0) active[cur ^ 1] = 0;  // reset next-flag
    if (!active[cur]) return;
    const int tid = threadIdx.x;
    const int w = tid >> 6, lane = tid & 63;
    const int quad = lane >> 4, vl = lane & 15;
    const int v0 = blockIdx.x * 64;
    const int vt = blockIdx.x * 4 + w;

    __shared__ float std_s[64][68];
    __shared__ unsigned long long wk[4][64];
    #pragma unroll
    for (int i = 0; i < 4; ++i) {
        const int p = i * 256 + tid;            // 1024 float4 loads
        const int row = p >> 4, cc = (p & 15) * 4;
        // std is a dead stream (read once per run): non-temporal so it does not
        // evict the 165 MB packed-weight working set from L3.
        const f32x4 sv = __builtin_nontemporal_load(
            (const f32x4*)&std_[((size_t)t * B + row) * V + v0 + cc]);
        *(f32x4*)&std_s[row][cc] = sv;
    }

    f32x4 acc0[4], acc1[4];
    #pragma unroll
    for (int mt = 0; mt < 4; ++mt) {
        acc0[mt] = (f32x4){0.f, 0.f, 0.f, 0.f};
        acc1[mt] = (f32x4){0.f, 0.f, 0.f, 0.f};
    }
    for (int c = 0; c < 32; ++c) {
        const size_t wpos = ((size_t)(vt * 32 + c) * 64 + lane) * 8;
        const half8 whi = *(const half8*)&Whi[wpos];
        const half8 wlo = *(const half8*)&Wlo[wpos];
        #pragma unroll
        for (int mt = 0; mt < 4; ++mt) {
            const size_t apos = ((size_t)(c * 4 + mt) * 64 + lane) * 8;
            const half8 ahi = *(const half8*)&Ahh[apos];
            const half8 alo = *(const half8*)&Ahl[apos];
            acc0[mt] = __builtin_amdgcn_mfma_f32_16x16x32_f16(ahi, whi, acc0[mt], 0, 0, 0);
            acc1[mt] = __builtin_amdgcn_mfma_f32_16x16x32_f16(ahi, wlo, acc1[mt], 0, 0, 0);
            acc1[mt] = __builtin_amdgcn_mfma_f32_16x16x32_f16(alo, whi, acc1[mt], 0, 0, 0);
        }
    }
    __syncthreads();

    const float outb = out_b[vt * 16 + vl];
    const int v = vt * 16 + vl;
    #pragma unroll
    for (int mt = 0; mt < 4; ++mt) {
        #pragma unroll
        for (int r = 0; r < 4; ++r) {
            const int b = mt * 16 + quad * 4 + r;
            const float val = acc0[mt][r] * INV_HI + acc1[mt][r] * INV_LO
                            + outb + std_s[b][w * 16 + vl];
            const uint32_t fb = __float_as_uint(val);
            const uint32_t mk = (fb & 0x80000000u) ? ~fb : (fb | 0x80000000u);
            unsigned long long key = ((unsigned long long)mk << 32)
                                   | (unsigned)(0x7FFFFFFF - v);
            #pragma unroll
            for (int m = 1; m < 16; m <<= 1) {
                const unsigned long long o = __shfl_xor(key, m, 16);
                if (o > key) key = o;
            }
            if (vl == 0) wk[w][b] = key;
        }
    }
    __syncthreads();
    if (tid < 64) {
        unsigned long long k0 = wk[0][tid];
        const unsigned long long k1 = wk[1][tid], k2 = wk[2][tid], k3 = wk[3][tid];
        if (k1 > k0) k0 = k1;
        if (k2 > k0) k0 = k2;
        if (k3 > k0) k0 = k3;
        atomicMax(&keys[tid], k0);
    }

    // ---- arrival counter: last block finalizes the step --------------------
    __shared__ int lastFlag;
    if (tid == 0) {
        __threadfence();                         // publish our keys/active updates
        lastFlag = (atomicAdd(cnt, 1) == (int)gridDim.x - 1);
    }
    __syncthreads();
    if (!lastFlag) return;
    __threadfence();                             // acquire: see all blocks' keys

    if (tid == 0) cnt[0] = 0;                    // rearm for next step
    __shared__ int toks[64];
    if (tid < 64) {
        const unsigned long long kk = keys[tid];
        const int tokn = 0x7FFFFFFF - (int)(unsigned)(kk & 0xFFFFFFFFull);
        toks[tid] = tokn;
        out[t * B + tid] = (float)tokn;
        keys[tid] = 0ull;
        if (tokn > 0) atomicOr(&active[cur ^ 1], 1);
    }
    __syncthreads();
    // pack emb[tok] -> Ax fragments: thread covers b = tid>>2, 256 k each
    const int b = tid >> 2, seg = tid & 3;
    const int tokn = toks[b];
    const float* er = emb + (size_t)tokn * H;
    const int mt = b >> 4;
    #pragma unroll 4
    for (int i = 0; i < 32; ++i) {
        const int kk0 = seg * 256 + i * 8;
        const f32x4 x0 = *(const f32x4*)&er[kk0];
        const f32x4 x1 = *(const f32x4*)&er[kk0 + 4];
        const float xs[8] = {x0.x, x0.y, x0.z, x0.w, x1.x, x1.y, x1.z, x1.w};
        half8 h8, l8;
        #pragma unroll
        for (int j = 0; j < 8; ++j) {
            const f16 hi = (f16)xs[j];
            h8[j] = hi;
            l8[j] = (f16)((xs[j] - (float)hi) * SL);
        }
        const int chunk = kk0 >> 5, lane2 = ((kk0 >> 3) & 3) * 16 + (b & 15);
        const size_t pos = ((size_t)(chunk * 4 + mt) * 64 + lane2) * 8;
        *(half8*)&Axh[pos] = h8;
        *(half8*)&Axl[pos] = l8;
    }
}

__global__ void k_fin(const float* __restrict__ h_t, float* __restrict__ out)
{
    const int idx = blockIdx.x * 256 + threadIdx.x;
    const int b = idx >> 10, k = idx & 1023;
    out[T * B + idx] = h_t[k * B + b];
}

extern "C" void kernel_launch(void* const* d_in, const int* in_sizes, int n_in,
                              void* d_out, int out_size, void* d_ws, size_t ws_size,
                              hipStream_t stream)
{
    const float* std_  = (const float*)d_in[1];
    const float* h_in  = (const float*)d_in[2];
    const float* c_in  = (const float*)d_in[3];
    const float* emb   = (const float*)d_in[4];
    const float* w_ih  = (const float*)d_in[5];
    const float* w_hh  = (const float*)d_in[6];
    const float* b_ih  = (const float*)d_in[7];
    const float* b_hh  = (const float*)d_in[8];
    const float* out_w = (const float*)d_in[9];
    const float* out_b = (const float*)d_in[10];
    float* out = (float*)d_out;

    // ---- workspace carve-up (halves first, 16B-aligned chunks) ----
    f16* Whi = (f16*)d_ws;                    // H*V
    f16* Wlo = Whi + (size_t)H * V;
    f16* Ghi = Wlo + (size_t)H * V;           // 2048*4096
    f16* Glo = Ghi + (size_t)2048 * 4096;
    f16* Axh = Glo + (size_t)2048 * 4096;     // B*H each
    f16* Axl = Axh + B * H;
    f16* Ah0h = Axl + B * H;
    f16* Ah0l = Ah0h + B * H;
    f16* Ah1h = Ah0l + B * H;
    f16* Ah1l = Ah1h + B * H;
    float* biasp = (float*)(Ah1l + B * H);    // 4096
    float* h_t = biasp + 4096;                // B*H
    float* c_t = h_t + B * H;                 // B*H
    unsigned long long* keys = (unsigned long long*)(c_t + B * H);  // 64
    int* active = (int*)(keys + B);           // 2
    int* cnt = active + 2;                    // 1 arrival counter

    f16* AhH[2] = {Ah0h, Ah1h};
    f16* AhL[2] = {Ah0l, Ah1l};

    k_packw<<<VT * 8, 256, 0, stream>>>(out_w, Whi, Wlo);
    k_packg<<<GNT * 16, 256, 0, stream>>>(w_ih, w_hh, Ghi, Glo);
    k_init<<<81, 256, 0, stream>>>(h_in, c_in, emb, b_ih, b_hh, h_t, c_t, Axh, Axl,
                                   Ah0h, Ah0l, keys, active, cnt, out, biasp);
    for (int t = 0; t < T; ++t) {
        const int cur = t & 1, nxt = cur ^ 1;
        k_gates<<<GNT, 256, 0, stream>>>(Ghi, Glo, Axh, Axl, AhH[cur], AhL[cur],
                                         AhH[nxt], AhL[nxt], biasp, h_t, c_t, active, t);
        k_logits<<<V / 64, 256, 0, stream>>>(AhH[nxt], AhL[nxt], Whi, Wlo,
                                             out_b, std_, emb, keys, active, cnt,
                                             out, Axh, Axl, t);
    }
    k_fin<<<256, 256, 0, stream>>>(h_t, out);
}